// Round 1
// baseline (30.460 us; speedup 1.0000x reference)
//
#include <hip/hip_runtime.h>
#include <math.h>

// TransitionGNN: N=16384, K=32, N_OF=7, N_EF=1, H=1
// All linear layers are scalar (H=1); fuse entire network into one kernel.
// One block per graph n; 256 threads; each thread handles 4 edges (float4).

#define KK 32

__global__ __launch_bounds__(256) void gnn_fused_kernel(
    const float* __restrict__ of,    // (N,32,7)
    const float* __restrict__ ef,    // (N,32,32,1)
    const float* __restrict__ act,   // (N,7)
    const float* __restrict__ W_ni,  // (14,1)
    const float* __restrict__ b_ni,  // (1,)
    const float* __restrict__ W_e,   // (3,1)
    const float* __restrict__ b_e,   // (1,)
    const float* __restrict__ W_n,   // (1,1)
    const float* __restrict__ b_n,   // (1,)
    const float* __restrict__ W_ef,  // (1,1)
    const float* __restrict__ b_ef,  // (1,)
    float* __restrict__ out)         // (N,32,32,1)
{
    const int n = blockIdx.x;
    const int t = threadIdx.x;

    __shared__ float s_hn[KK];
    __shared__ float s_row[KK];
    __shared__ float s_hn2[KK];

    // Uniform scalar weights (broadcast loads, L1-cached).
    const float we0 = W_e[0], we1 = W_e[1], we2 = W_e[2], be = b_e[0];
    const float wn  = W_n[0],  bn  = b_n[0];
    const float wef = W_ef[0], bef = b_ef[0];

    // ---- Step 1: hn[i] for i in [0,32) ----
    if (t < KK) {
        const float* ofp = of + ((size_t)n * KK + t) * 7;
        const float* ap  = act + (size_t)n * 7;
        float s = b_ni[0];
        #pragma unroll
        for (int f = 0; f < 7; ++f) s += ofp[f] * W_ni[f];
        #pragma unroll
        for (int f = 0; f < 7; ++f) s += ap[f] * W_ni[7 + f];
        s_hn[t] = s;
    }
    __syncthreads();

    // ---- Step 2: first edge pass + row-sum over j ----
    // Thread t owns edges (i = t>>3, j = (t&7)*4 .. +3). ef kept in regs.
    const int i  = t >> 3;
    const int j0 = (t & 7) * 4;
    const float4 e4 = *reinterpret_cast<const float4*>(
        ef + ((size_t)n * KK + i) * KK + j0);

    const float hni = s_hn[i];
    const float hj0 = s_hn[j0 + 0], hj1 = s_hn[j0 + 1];
    const float hj2 = s_hn[j0 + 2], hj3 = s_hn[j0 + 3];

    float part =
        fmaxf(fmaf(we2, e4.x, fmaf(we1, hj0, fmaf(we0, hni, be))), 0.f) +
        fmaxf(fmaf(we2, e4.y, fmaf(we1, hj1, fmaf(we0, hni, be))), 0.f) +
        fmaxf(fmaf(we2, e4.z, fmaf(we1, hj2, fmaf(we0, hni, be))), 0.f) +
        fmaxf(fmaf(we2, e4.w, fmaf(we1, hj3, fmaf(we0, hni, be))), 0.f);

    // Reduce across the 8 lanes sharing i (contiguous lanes in the wave).
    part += __shfl_xor(part, 1);
    part += __shfl_xor(part, 2);
    part += __shfl_xor(part, 4);
    if ((t & 7) == 0) s_row[i] = part;
    __syncthreads();

    // ---- Step 3: node update ----
    if (t < KK) s_hn2[t] = fmaxf(fmaf(wn, s_row[t], bn), 0.f);
    __syncthreads();

    // ---- Step 4: second edge pass + readout + sigmoid ----
    const float g_i  = s_hn2[i];
    const float g_j0 = s_hn2[j0 + 0], g_j1 = s_hn2[j0 + 1];
    const float g_j2 = s_hn2[j0 + 2], g_j3 = s_hn2[j0 + 3];

    float4 o4;
    {
        float v = fmaxf(fmaf(we2, e4.x, fmaf(we1, g_j0, fmaf(we0, g_i, be))), 0.f);
        v = fmaxf(fmaf(wef, v, bef), 0.f);
        o4.x = 1.f / (1.f + expf(-v));
    }
    {
        float v = fmaxf(fmaf(we2, e4.y, fmaf(we1, g_j1, fmaf(we0, g_i, be))), 0.f);
        v = fmaxf(fmaf(wef, v, bef), 0.f);
        o4.y = 1.f / (1.f + expf(-v));
    }
    {
        float v = fmaxf(fmaf(we2, e4.z, fmaf(we1, g_j2, fmaf(we0, g_i, be))), 0.f);
        v = fmaxf(fmaf(wef, v, bef), 0.f);
        o4.z = 1.f / (1.f + expf(-v));
    }
    {
        float v = fmaxf(fmaf(we2, e4.w, fmaf(we1, g_j3, fmaf(we0, g_i, be))), 0.f);
        v = fmaxf(fmaf(wef, v, bef), 0.f);
        o4.w = 1.f / (1.f + expf(-v));
    }

    *reinterpret_cast<float4*>(out + ((size_t)n * KK + i) * KK + j0) = o4;
}

extern "C" void kernel_launch(void* const* d_in, const int* in_sizes, int n_in,
                              void* d_out, int out_size, void* d_ws, size_t ws_size,
                              hipStream_t stream) {
    const float* of   = (const float*)d_in[0];
    const float* ef   = (const float*)d_in[1];
    const float* act  = (const float*)d_in[2];
    const float* W_ni = (const float*)d_in[3];
    const float* b_ni = (const float*)d_in[4];
    const float* W_e  = (const float*)d_in[5];
    const float* b_e  = (const float*)d_in[6];
    const float* W_n  = (const float*)d_in[7];
    const float* b_n  = (const float*)d_in[8];
    const float* W_ef = (const float*)d_in[9];
    const float* b_ef = (const float*)d_in[10];
    float* out = (float*)d_out;

    const int N = in_sizes[2] / 7;  // action is (N,7)
    gnn_fused_kernel<<<N, 256, 0, stream>>>(
        of, ef, act, W_ni, b_ni, W_e, b_e, W_n, b_n, W_ef, b_ef, out);
}

// Round 2
// 28.273 us; speedup vs baseline: 1.0773x; 1.0773x over previous
//
#include <hip/hip_runtime.h>
#include <math.h>

// TransitionGNN: N=16384, K=32, N_OF=7, N_EF=1, H=1  -> all layers scalar.
// Wave-per-graph design: one 64-lane wave handles one full 32x32 edge tile
// (16 edges/lane = 4x float4 loads, perfectly coalesced). No LDS, no
// __syncthreads -- all cross-lane communication via shuffles. Nontemporal
// stores for the 64 MB output keep ef L3-resident across replays.

typedef float v4f __attribute__((ext_vector_type(4)));

__global__ __launch_bounds__(256) void gnn_fused_kernel(
    const float* __restrict__ of,    // (N,32,7)
    const float* __restrict__ ef,    // (N,32,32)
    const float* __restrict__ act,   // (N,7)
    const float* __restrict__ W_ni,  // (14,)
    const float* __restrict__ b_ni,  // (1,)
    const float* __restrict__ W_e,   // (3,)
    const float* __restrict__ b_e,   // (1,)
    const float* __restrict__ W_n,   // (1,)
    const float* __restrict__ b_n,   // (1,)
    const float* __restrict__ W_ef,  // (1,)
    const float* __restrict__ b_ef,  // (1,)
    float* __restrict__ out,         // (N,32,32)
    int Ntot)
{
    const int wv = threadIdx.x >> 6;           // wave id in block (0..3)
    const int l  = threadIdx.x & 63;           // lane
    const int n  = blockIdx.x * 4 + wv;        // graph index
    if (n >= Ntot) return;

    // ---- Issue all 16 ef loads up front (4x dwordx4, coalesced) ----
    const float* efp = ef + (size_t)n * 1024;
    float4 e[4];
    #pragma unroll
    for (int q = 0; q < 4; ++q)
        e[q] = *reinterpret_cast<const float4*>(efp + q * 256 + l * 4);

    // Uniform scalar weights.
    const float we0 = W_e[0], we1 = W_e[1], we2 = W_e[2], be = b_e[0];
    const float wn  = W_n[0],  bn  = b_n[0];
    const float wef = W_ef[0], bef = b_ef[0];

    // ---- Step 1: hn[l] on lanes 0..31 (node embedding, H=1) ----
    float hn_own = 0.f;
    if (l < 32) {
        const float* ofp = of + ((size_t)n * 32 + l) * 7;
        const float* ap  = act + (size_t)n * 7;
        float s = b_ni[0];
        #pragma unroll
        for (int f = 0; f < 7; ++f) s = fmaf(ofp[f], W_ni[f], s);
        #pragma unroll
        for (int f = 0; f < 7; ++f) s = fmaf(ap[f], W_ni[7 + f], s);
        hn_own = s;
    }

    // Edge ownership: flat index f = q*256 + l*4 + k  ->  i = q*8 + (l>>3),
    // j = (l&7)*4 + k.  Each row i is covered by the 8 lanes sharing l>>3.
    const int m     = l >> 3;        // row-group 0..7
    const int jbase = (l & 7) * 4;   // column base

    float hn_j[4];
    #pragma unroll
    for (int k = 0; k < 4; ++k) hn_j[k] = __shfl(hn_own, jbase + k);

    // ---- Step 2: first edge pass + per-row sums (butterfly in 8-lane grp) ----
    float s_q[4];
    #pragma unroll
    for (int q = 0; q < 4; ++q) {
        const float hni = __shfl(hn_own, q * 8 + m);
        const float a   = fmaf(we0, hni, be);
        const float* ec = reinterpret_cast<const float*>(&e[q]);
        float p = 0.f;
        #pragma unroll
        for (int k = 0; k < 4; ++k)
            p += fmaxf(fmaf(we2, ec[k], fmaf(we1, hn_j[k], a)), 0.f);
        p += __shfl_xor(p, 1);
        p += __shfl_xor(p, 2);
        p += __shfl_xor(p, 4);
        s_q[q] = p;   // row (q*8+m) sum, valid in all 8 lanes of group m
    }

    // ---- Redistribute row sums: lane wants row r = l&31 ----
    // row r lives as s_{r>>3} in lane group (r&7); pull from lane (l&7)*8.
    float a0 = __shfl(s_q[0], (l & 7) * 8);
    float a1 = __shfl(s_q[1], (l & 7) * 8);
    float a2 = __shfl(s_q[2], (l & 7) * 8);
    float a3 = __shfl(s_q[3], (l & 7) * 8);
    float b0 = (l & 8)  ? a1 : a0;
    float b1 = (l & 8)  ? a3 : a2;
    float sum_own = (l & 16) ? b1 : b0;

    // ---- Step 3: node update ----
    const float hn2_own = fmaxf(fmaf(wn, sum_own, bn), 0.f);  // row l&31

    float g_j[4];
    #pragma unroll
    for (int k = 0; k < 4; ++k) g_j[k] = __shfl(hn2_own, jbase + k);

    // ---- Step 4: second edge pass + readout + sigmoid, nt store ----
    float* outp = out + (size_t)n * 1024;
    #pragma unroll
    for (int q = 0; q < 4; ++q) {
        const float g_i = __shfl(hn2_own, q * 8 + m);
        const float a   = fmaf(we0, g_i, be);
        const float* ec = reinterpret_cast<const float*>(&e[q]);
        v4f o;
        #pragma unroll
        for (int k = 0; k < 4; ++k) {
            float v = fmaxf(fmaf(we2, ec[k], fmaf(we1, g_j[k], a)), 0.f);
            v = fmaxf(fmaf(wef, v, bef), 0.f);
            o[k] = 1.f / (1.f + __expf(-v));
        }
        __builtin_nontemporal_store(o, (v4f*)(outp + q * 256 + l * 4));
    }
}

extern "C" void kernel_launch(void* const* d_in, const int* in_sizes, int n_in,
                              void* d_out, int out_size, void* d_ws, size_t ws_size,
                              hipStream_t stream) {
    const float* of   = (const float*)d_in[0];
    const float* ef   = (const float*)d_in[1];
    const float* act  = (const float*)d_in[2];
    const float* W_ni = (const float*)d_in[3];
    const float* b_ni = (const float*)d_in[4];
    const float* W_e  = (const float*)d_in[5];
    const float* b_e  = (const float*)d_in[6];
    const float* W_n  = (const float*)d_in[7];
    const float* b_n  = (const float*)d_in[8];
    const float* W_ef = (const float*)d_in[9];
    const float* b_ef = (const float*)d_in[10];
    float* out = (float*)d_out;

    const int N = in_sizes[2] / 7;  // action is (N,7)
    const int blocks = (N + 3) / 4; // 4 graphs (waves) per block
    gnn_fused_kernel<<<blocks, 256, 0, stream>>>(
        of, ef, act, W_ni, b_ni, W_e, b_e, W_n, b_n, W_ef, b_ef, out, N);
}

// Round 3
// 27.390 us; speedup vs baseline: 1.1121x; 1.0323x over previous
//
#include <hip/hip_runtime.h>
#include <math.h>

// TransitionGNN: N=16384, K=32, N_OF=7, N_EF=1, H=1 -> all layers scalar.
// Wave-per-graph. ef held in registers (16 edges/lane via 4x dwordx4) and
// reused for both edge passes. Cross-lane: DPP adds for the 8-lane row
// reduce (VALU-rate), tiny per-wave LDS arrays for the hn/hn2 gathers
// (wave-synchronous, no barriers). Nontemporal float4 stores for the
// 64 MB output stream.

typedef float v4f __attribute__((ext_vector_type(4)));

#define DPP_ADD(p, ctrl)                                                  \
    ((p) + __int_as_float(__builtin_amdgcn_mov_dpp(                       \
               __float_as_int(p), (ctrl), 0xf, 0xf, true)))

__global__ __launch_bounds__(256) void gnn_fused_kernel(
    const float* __restrict__ of,    // (N,32,7)
    const float* __restrict__ ef,    // (N,32,32)
    const float* __restrict__ act,   // (N,7)
    const float* __restrict__ W_ni,  // (14,)
    const float* __restrict__ b_ni,  // (1,)
    const float* __restrict__ W_e,   // (3,)
    const float* __restrict__ b_e,   // (1,)
    const float* __restrict__ W_n,   // (1,)
    const float* __restrict__ b_n,   // (1,)
    const float* __restrict__ W_ef,  // (1,)
    const float* __restrict__ b_ef,  // (1,)
    float* __restrict__ out,         // (N,32,32)
    int Ntot)
{
    const int wv = threadIdx.x >> 6;           // wave in block (0..3)
    const int l  = threadIdx.x & 63;           // lane
    const int n  = blockIdx.x * 4 + wv;        // graph index
    if (n >= Ntot) return;

    __shared__ __align__(16) float sh_hn[4][32];
    __shared__ __align__(16) float sh_hn2[4][32];
    float* hn_lds  = sh_hn[wv];
    float* hn2_lds = sh_hn2[wv];

    // ---- all 16 ef loads up front (4x dwordx4, coalesced) ----
    const float* efp = ef + (size_t)n * 1024 + l * 4;
    const float4 e0 = *reinterpret_cast<const float4*>(efp);
    const float4 e1 = *reinterpret_cast<const float4*>(efp + 256);
    const float4 e2 = *reinterpret_cast<const float4*>(efp + 512);
    const float4 e3 = *reinterpret_cast<const float4*>(efp + 768);

    const float we0 = W_e[0], we1 = W_e[1], we2 = W_e[2], be = b_e[0];
    const float wn  = W_n[0],  bn  = b_n[0];
    const float wef = W_ef[0], bef = b_ef[0];

    // ---- Step 1: hn for node (l&31); upper half-wave duplicates ----
    {
        const float* ofp = of + ((size_t)n * 32 + (l & 31)) * 7;
        const float* ap  = act + (size_t)n * 7;
        float s = b_ni[0];
        #pragma unroll
        for (int f = 0; f < 7; ++f) s = fmaf(ofp[f], W_ni[f], s);
        #pragma unroll
        for (int f = 0; f < 7; ++f) s = fmaf(ap[f], W_ni[7 + f], s);
        hn_lds[l & 31] = s;           // 2-way dup write (free)
    }
    __builtin_amdgcn_wave_barrier();

    // Edge ownership: lane l, quad q -> row i = q*8 + (l>>3),
    // cols j = (l&7)*4 .. +3.
    const int m     = l >> 3;
    const int jbase = (l & 7) * 4;

    const float4 hj = *reinterpret_cast<const float4*>(&hn_lds[jbase]); // b128
    const float hi0 = hn_lds[m];          // ds_read2 pairs
    const float hi1 = hn_lds[m + 8];
    const float hi2 = hn_lds[m + 16];
    const float hi3 = hn_lds[m + 24];

    // ---- Step 2: first edge pass + DPP row-sum reduce ----
    auto rowsum = [&](const float4& e, float hi) {
        const float a = fmaf(we0, hi, be);
        float p = fmaxf(fmaf(we2, e.x, fmaf(we1, hj.x, a)), 0.f)
                + fmaxf(fmaf(we2, e.y, fmaf(we1, hj.y, a)), 0.f)
                + fmaxf(fmaf(we2, e.z, fmaf(we1, hj.z, a)), 0.f)
                + fmaxf(fmaf(we2, e.w, fmaf(we1, hj.w, a)), 0.f);
        p = DPP_ADD(p, 0xB1);   // quad_perm [1,0,3,2]  : xor 1
        p = DPP_ADD(p, 0x4E);   // quad_perm [2,3,0,1]  : xor 2
        p = DPP_ADD(p, 0x141);  // row_half_mirror      : xor 4 (uniform quads)
        return p;               // full row sum in all 8 lanes of group m
    };
    const float s0 = rowsum(e0, hi0);
    const float s1 = rowsum(e1, hi1);
    const float s2 = rowsum(e2, hi2);
    const float s3 = rowsum(e3, hi3);

    // ---- Step 3: node update; g_q = hn2[q*8+m] stays in-lane ----
    const float g0 = fmaxf(fmaf(wn, s0, bn), 0.f);
    const float g1 = fmaxf(fmaf(wn, s1, bn), 0.f);
    const float g2 = fmaxf(fmaf(wn, s2, bn), 0.f);
    const float g3 = fmaxf(fmaf(wn, s3, bn), 0.f);

    if ((l & 7) == 0) {                   // one writer per row group
        hn2_lds[m]      = g0;
        hn2_lds[m + 8]  = g1;
        hn2_lds[m + 16] = g2;
        hn2_lds[m + 24] = g3;
    }
    __builtin_amdgcn_wave_barrier();
    const float4 gj = *reinterpret_cast<const float4*>(&hn2_lds[jbase]);

    // ---- Step 4: second edge pass + readout + sigmoid, nt stores ----
    float* outp = out + (size_t)n * 1024 + l * 4;
    auto edge2 = [&](const float4& e, float gi, float* dst) {
        const float a = fmaf(we0, gi, be);
        v4f o;
        {
            float v = fmaxf(fmaf(we2, e.x, fmaf(we1, gj.x, a)), 0.f);
            v = fmaxf(fmaf(wef, v, bef), 0.f);
            o.x = __builtin_amdgcn_rcpf(1.f + __builtin_amdgcn_exp2f(v * -1.44269504089f));
        }
        {
            float v = fmaxf(fmaf(we2, e.y, fmaf(we1, gj.y, a)), 0.f);
            v = fmaxf(fmaf(wef, v, bef), 0.f);
            o.y = __builtin_amdgcn_rcpf(1.f + __builtin_amdgcn_exp2f(v * -1.44269504089f));
        }
        {
            float v = fmaxf(fmaf(we2, e.z, fmaf(we1, gj.z, a)), 0.f);
            v = fmaxf(fmaf(wef, v, bef), 0.f);
            o.z = __builtin_amdgcn_rcpf(1.f + __builtin_amdgcn_exp2f(v * -1.44269504089f));
        }
        {
            float v = fmaxf(fmaf(we2, e.w, fmaf(we1, gj.w, a)), 0.f);
            v = fmaxf(fmaf(wef, v, bef), 0.f);
            o.w = __builtin_amdgcn_rcpf(1.f + __builtin_amdgcn_exp2f(v * -1.44269504089f));
        }
        __builtin_nontemporal_store(o, (v4f*)dst);
    };
    edge2(e0, g0, outp);
    edge2(e1, g1, outp + 256);
    edge2(e2, g2, outp + 512);
    edge2(e3, g3, outp + 768);
}

extern "C" void kernel_launch(void* const* d_in, const int* in_sizes, int n_in,
                              void* d_out, int out_size, void* d_ws, size_t ws_size,
                              hipStream_t stream) {
    const float* of   = (const float*)d_in[0];
    const float* ef   = (const float*)d_in[1];
    const float* act  = (const float*)d_in[2];
    const float* W_ni = (const float*)d_in[3];
    const float* b_ni = (const float*)d_in[4];
    const float* W_e  = (const float*)d_in[5];
    const float* b_e  = (const float*)d_in[6];
    const float* W_n  = (const float*)d_in[7];
    const float* b_n  = (const float*)d_in[8];
    const float* W_ef = (const float*)d_in[9];
    const float* b_ef = (const float*)d_in[10];
    float* out = (float*)d_out;

    const int N = in_sizes[2] / 7;   // action is (N,7)
    const int blocks = (N + 3) / 4;  // 4 graphs (waves) per block
    gnn_fused_kernel<<<blocks, 256, 0, stream>>>(
        of, ef, act, W_ni, b_ni, W_e, b_e, W_n, b_n, W_ef, b_ef, out, N);
}